// Round 8
// baseline (291.866 us; speedup 1.0000x reference)
//
#include <hip/hip_runtime.h>
#include <hip/hip_bf16.h>

typedef unsigned short u16;
typedef unsigned int   u32;

typedef __bf16 bf16x8 __attribute__((ext_vector_type(8)));
typedef float  f32x4  __attribute__((ext_vector_type(4)));

#define GLDS(gp, lp) __builtin_amdgcn_global_load_lds( \
    (const __attribute__((address_space(1))) void*)(gp), \
    (__attribute__((address_space(3))) void*)(lp), 16, 0, 0)

__device__ __forceinline__ u16 f2b(float f) {
    __hip_bfloat16 h = __float2bfloat16(f);
    u16 u; __builtin_memcpy(&u, &h, 2); return u;
}
__device__ __forceinline__ float blo(u32 u) { return __uint_as_float(u << 16); }
__device__ __forceinline__ float bhi(u32 u) { return __uint_as_float(u & 0xffff0000u); }

// ---------------------------------------------------------------------------
// fused prep:
//  section A (blocks [0,4356)):    zero-padded bf16 input (16,66,66,128)
//  section B (blocks [4356,5508)): weights -> MFMA B-fragment order
//       BF[(((p*4+kk)*4+q)*256 + n)*8 + j] = bf16(w[(p*128+kk*32+q*8+j)*256+n])
//  section C (blocks [5508,5557)): zero s0,s2,s3 + barrier counters (12544 f)
// ---------------------------------------------------------------------------
__global__ void k_prep(const float* __restrict__ in, const float* __restrict__ wk,
                       u16* __restrict__ pad, u16* __restrict__ BF,
                       float* __restrict__ stats) {
    int bx = blockIdx.x, tid = threadIdx.x;
    if (bx < 4356) {
        int idx = bx * 256 + tid;                 // one 8-channel chunk each
        int e0  = idx * 8;
        int ch  = e0 & 127;
        int rest = e0 >> 7;                       // (b*66+ph)*66+pw
        int pw = rest % 66;
        int r2 = rest / 66;
        int ph = r2 % 66;
        int b  = r2 / 66;
        u16 ov[8];
        if (ph >= 1 && ph <= 64 && pw >= 1 && pw <= 64) {
            const float* src = in + (((b * 64 + (ph - 1)) * 64 + (pw - 1)) * 128 + ch);
            const float4* s4 = (const float4*)src;
            float4 f0 = s4[0], f1 = s4[1];
            ov[0]=f2b(f0.x); ov[1]=f2b(f0.y); ov[2]=f2b(f0.z); ov[3]=f2b(f0.w);
            ov[4]=f2b(f1.x); ov[5]=f2b(f1.y); ov[6]=f2b(f1.z); ov[7]=f2b(f1.w);
        } else {
            #pragma unroll
            for (int j = 0; j < 8; ++j) ov[j] = 0;
        }
        uint4 w; __builtin_memcpy(&w, ov, 16);
        *(uint4*)(pad + e0) = w;
    } else if (bx < 5508) {
        int t = (bx - 4356) * 256 + tid;          // 294912 total, exact
        int j  = t & 7;
        int n  = (t >> 3) & 255;
        int q  = (t >> 11) & 3;
        int kk = (t >> 13) & 3;
        int p  = t >> 15;
        BF[t] = f2b(wk[(p * 128 + kk * 32 + q * 8 + j) * 256 + n]);
    } else {
        stats[(bx - 5508) * 256 + tid] = 0.f;     // 12544 floats (incl. counters)
    }
}

// ---------------------------------------------------------------------------
// conv: implicit GEMM (R4 structure — best measured, no spill).
// Block = one image row: M=64, N=256, K=1152. 4 waves, wave tile 64x64
// (4x4 16x16x32 bf16 MFMA). A staged by channel half (25344 B LDS, swizzled
// source gather); B fragments straight from L2 in fragment order, register
// ping-pong, barrier-free K-loop.
// Epilogue: +bias, relu, store x bf16, atomically accumulate s0 = sum_n x.
// ---------------------------------------------------------------------------
__launch_bounds__(256, 2)
__global__ void k_conv(const u16* __restrict__ Ap, const u16* __restrict__ BF,
                       const float* __restrict__ bias,
                       u16* __restrict__ X, float* __restrict__ s0) {
    __shared__ u16 ldsA[12672];                   // 3*66*8 chunks = 25344 B
    const int t = threadIdx.x;
    const int lane = t & 63, wid = t >> 6;        // 4 waves
    const int q = lane >> 4, l15 = lane & 15;
    const int bb = blockIdx.x >> 6;               // batch
    const int h  = blockIdx.x & 63;               // output row
    const int wn0 = wid << 6;                     // wave's n-offset (64 each)

    // stage channel-half S: LDS[pr][wp][cs] = G[S*8 + (cs^(wp&7))] (src swizzle)
#define STAGE(S) { \
    const int sb0 = wid * 396; \
    _Pragma("unroll") for (int i = 0; i < 6; ++i) { \
        int sb = sb0 + i * 64; \
        int slot = sb + lane; \
        int pr = slot / 528; int rem = slot - pr * 528; \
        int wp = rem >> 3, cs = rem & 7; \
        int gc = (S) * 8 + (cs ^ (wp & 7)); \
        const u16* g = Ap + ((((bb * 66 + h + pr) * 66 + wp) << 7) + (gc << 3)); \
        GLDS(g, (char*)ldsA + sb * 16); \
    } \
    { int sb = sb0 + 384; \
      if (lane < 12) { \
        int slot = sb + lane; \
        int pr = slot / 528; int rem = slot - pr * 528; \
        int wp = rem >> 3, cs = rem & 7; \
        int gc = (S) * 8 + (cs ^ (wp & 7)); \
        const u16* g = Ap + ((((bb * 66 + h + pr) * 66 + wp) << 7) + (gc << 3)); \
        GLDS(g, (char*)ldsA + sb * 16); \
      } } }

#define LOADB(B, P, S) { \
    _Pragma("unroll") for (int kk = 0; kk < 2; ++kk) \
    _Pragma("unroll") for (int ni = 0; ni < 4; ++ni) \
        B[kk * 4 + ni] = *(const bf16x8*)(BFl + (P) * 32768 + \
                                          ((S) * 2 + kk) * 8192 + ni * 128); }

#define COMPP(B, DH, DW) { \
    _Pragma("unroll") for (int kk = 0; kk < 2; ++kk) { \
        bf16x8 af[4]; \
        _Pragma("unroll") for (int mi = 0; mi < 4; ++mi) { \
            int wp = mi * 16 + l15 + (DW); \
            int swz = (kk * 4 + q) ^ (wp & 7); \
            af[mi] = *(const bf16x8*)((const char*)ldsA + \
                (((DH) * 528 + wp * 8 + swz) << 4)); \
        } \
        _Pragma("unroll") for (int mi = 0; mi < 4; ++mi) \
        _Pragma("unroll") for (int ni = 0; ni < 4; ++ni) \
            acc[mi][ni] = __builtin_amdgcn_mfma_f32_16x16x32_bf16( \
                af[mi], B[kk * 4 + ni], acc[mi][ni], 0, 0, 0); } }

    const u16* BFl = BF + (q * 2048 + (wn0 + l15) * 8);

    f32x4 zero = {0.f, 0.f, 0.f, 0.f};
    f32x4 acc[4][4];
    #pragma unroll
    for (int mi = 0; mi < 4; ++mi)
        #pragma unroll
        for (int ni = 0; ni < 4; ++ni) acc[mi][ni] = zero;

    bf16x8 B0[8], B1[8];

    // ---- channel half 0 ----
    STAGE(0);
    __syncthreads();
    LOADB(B0, 0, 0);
    LOADB(B1, 1, 0); COMPP(B0, 0, 0);
    LOADB(B0, 2, 0); COMPP(B1, 0, 1);
    LOADB(B1, 3, 0); COMPP(B0, 0, 2);
    LOADB(B0, 4, 0); COMPP(B1, 1, 0);
    LOADB(B1, 5, 0); COMPP(B0, 1, 1);
    LOADB(B0, 6, 0); COMPP(B1, 1, 2);
    LOADB(B1, 7, 0); COMPP(B0, 2, 0);
    LOADB(B0, 8, 0); COMPP(B1, 2, 1);
    COMPP(B0, 2, 2);
    __syncthreads();                              // all half-0 LDS reads done

    // ---- channel half 1 ----
    STAGE(1);
    __syncthreads();
    LOADB(B0, 0, 1);
    LOADB(B1, 1, 1); COMPP(B0, 0, 0);
    LOADB(B0, 2, 1); COMPP(B1, 0, 1);
    LOADB(B1, 3, 1); COMPP(B0, 0, 2);
    LOADB(B0, 4, 1); COMPP(B1, 1, 0);
    LOADB(B1, 5, 1); COMPP(B0, 1, 1);
    LOADB(B0, 6, 1); COMPP(B1, 1, 2);
    LOADB(B1, 7, 1); COMPP(B0, 2, 0);
    LOADB(B0, 8, 1); COMPP(B1, 2, 1);
    COMPP(B0, 2, 2);

    // epilogue: bias + relu, store bf16 x, column sums -> s0
    float bv[4];
    #pragma unroll
    for (int ni = 0; ni < 4; ++ni) bv[ni] = bias[wn0 + ni * 16 + l15];
    float colsum[4] = {0.f, 0.f, 0.f, 0.f};
    u16* xrow = X + (((bb << 12) + (h << 6) + q * 4) * 256) + wn0 + l15;
    #pragma unroll
    for (int mi = 0; mi < 4; ++mi) {
        #pragma unroll
        for (int rr = 0; rr < 4; ++rr) {
            u16* xp = xrow + (mi * 16 + rr) * 256;
            #pragma unroll
            for (int ni = 0; ni < 4; ++ni) {
                float v = acc[mi][ni][rr] + bv[ni];
                v = v > 0.f ? v : 0.f;
                xp[ni * 16] = f2b(v);
                colsum[ni] += v;
            }
        }
    }
    #pragma unroll
    for (int ni = 0; ni < 4; ++ni) {
        float c = colsum[ni];
        c += __shfl_xor(c, 16);
        c += __shfl_xor(c, 32);
        if (lane < 16) atomicAdd(&s0[bb * 256 + wn0 + ni * 16 + l15], c);
    }
#undef STAGE
#undef LOADB
#undef COMPP
}

// ---------------------------------------------------------------------------
// capacity-guaranteed grid barrier: 512 uniform blocks, __launch_bounds__
// (256,4) caps VGPR at 128 -> >=4 blocks/CU by all resources (LDS 18.4KB*4,
// 16 waves) -> capacity >=1024 >= grid 512 -> all blocks co-resident; a
// device-scope counter barrier cannot deadlock. Bounded spin as a fail-safe.
// ---------------------------------------------------------------------------
__device__ __forceinline__ void gridbar(u32* ctr, u32 nblk) {
    __syncthreads();
    if (threadIdx.x == 0) {
        __threadfence();                          // publish prior writes
        __hip_atomic_fetch_add(ctr, 1u, __ATOMIC_RELEASE, __HIP_MEMORY_SCOPE_AGENT);
        u32 v; unsigned long g = 0;
        do {
            v = __hip_atomic_load(ctr, __ATOMIC_ACQUIRE, __HIP_MEMORY_SCOPE_AGENT);
        } while (v < nblk && ++g < (1ul << 31));
    }
    __syncthreads();
}

// ---------------------------------------------------------------------------
// fused routing: pass1 -> bar -> pass2 -> bar -> bcast.  512 blocks x 256.
// Per pass: block = (b = bx>>5, chunk = bx&31), 128 positions, thread
// (c = t&15, nl = t>>4).  b-logits bounded -> softmax without max pass.
// ---------------------------------------------------------------------------
__launch_bounds__(256, 4)
__global__ void k_route(const u16* __restrict__ X, const float* __restrict__ s0,
                        float* __restrict__ s2, float* __restrict__ s3,
                        u32* __restrict__ bar, float* __restrict__ out) {
    __shared__ float v1s[256], v2s[256];
    __shared__ float red[4096];
    const int t = threadIdx.x, bx = blockIdx.x;
    const int b = bx >> 5, chunk = bx & 31;
    const int c = t & 15, nl = t >> 4;

#define PASS_BODY(SA_EXPR, SB_EXPR, USE2, SOUT) { \
    { \
        float sa = (SA_EXPR); \
        float ss = sa * sa; \
        _Pragma("unroll") \
        for (int off = 1; off < 16; off <<= 1) ss += __shfl_xor(ss, off); \
        ss = ss < 1e-12f ? 1e-12f : ss; \
        v1s[t] = sa / sqrtf(ss); \
        if (USE2) { \
            float sb = (SB_EXPR); \
            float s2v = sb * sb; \
            _Pragma("unroll") \
            for (int off = 1; off < 16; off <<= 1) s2v += __shfl_xor(s2v, off); \
            s2v = s2v < 1e-12f ? 1e-12f : s2v; \
            v2s[t] = sb / sqrtf(s2v); \
        } else { v2s[t] = 0.f; } \
    } \
    __syncthreads(); \
    float acc[16]; \
    _Pragma("unroll") for (int d = 0; d < 16; ++d) acc[d] = 0.f; \
    const u16* xbase = X + ((b << 12) + chunk * 128 + nl) * 256 + c * 16; \
    uint4 p0 = ((const uint4*)xbase)[0]; \
    uint4 p1 = ((const uint4*)xbase)[1]; \
    for (int r = 0; r < 8; ++r) { \
        uint4 a0 = p0, a1 = p1; \
        if (r < 7) { \
            const u16* np = xbase + (r + 1) * 16 * 256; \
            p0 = ((const uint4*)np)[0]; \
            p1 = ((const uint4*)np)[1]; \
        } \
        u32 us[8] = {a0.x, a0.y, a0.z, a0.w, a1.x, a1.y, a1.z, a1.w}; \
        float xf[16]; \
        _Pragma("unroll") \
        for (int j = 0; j < 8; ++j) { xf[2*j] = blo(us[j]); xf[2*j+1] = bhi(us[j]); } \
        float d1 = 0.f, d2 = 0.f; \
        _Pragma("unroll") \
        for (int d = 0; d < 16; ++d) { \
            d1 += xf[d] * v1s[c * 16 + d]; \
            d2 += xf[d] * v2s[c * 16 + d]; \
        } \
        float bvv = (USE2) ? (d1 + d2) : d1; \
        float e = __expf(bvv); \
        float sm = e; \
        _Pragma("unroll") \
        for (int off = 1; off < 16; off <<= 1) sm += __shfl_xor(sm, off); \
        float w = e / sm; \
        _Pragma("unroll") \
        for (int d = 0; d < 16; ++d) acc[d] += w * xf[d]; \
    } \
    _Pragma("unroll") \
    for (int d = 0; d < 16; ++d) red[t * 16 + d] = acc[d]; \
    __syncthreads(); \
    { \
        int c2 = t >> 4, d2i = t & 15; \
        float tot = 0.f; \
        _Pragma("unroll") \
        for (int n2 = 0; n2 < 16; ++n2) tot += red[(n2 * 16 + c2) * 16 + d2i]; \
        atomicAdd(&(SOUT)[b * 256 + c2 * 16 + d2i], tot); \
    } }

    // ---- phase 1: v1 = l2n(s0); s2 += sum c1*x ----
    PASS_BODY(s0[b * 256 + t], 0.f, 0, s2)
    gridbar(&bar[0], 512);

    // ---- phase 2: v1 = l2n(s0), v2 = l2n(s2); s3 += sum c2*x ----
    PASS_BODY(s0[b * 256 + t],
              __hip_atomic_load(&s2[b * 256 + t], __ATOMIC_RELAXED,
                                __HIP_MEMORY_SCOPE_AGENT), 1, s3)
    gridbar(&bar[1], 512);

    // ---- phase 3: v = l2n(s3); broadcast 128 positions x 256 ch fp32 ----
    {
        float s = __hip_atomic_load(&s3[b * 256 + t], __ATOMIC_RELAXED,
                                    __HIP_MEMORY_SCOPE_AGENT);
        float ss = s * s;
        #pragma unroll
        for (int off = 1; off < 16; off <<= 1) ss += __shfl_xor(ss, off);
        ss = ss < 1e-12f ? 1e-12f : ss;
        v1s[t] = s / sqrtf(ss);
    }
    __syncthreads();
    const float4* vls = (const float4*)v1s;
    float4* o = (float4*)out + (long)b * 262144 + chunk * 8192;
    #pragma unroll
    for (int j = 0; j < 32; ++j) {
        int idx = j * 256 + t;
        o[idx] = vls[idx & 63];
    }
#undef PASS_BODY
}

// ---------------------------------------------------------------------------
extern "C" void kernel_launch(void* const* d_in, const int* in_sizes, int n_in,
                              void* d_out, int out_size, void* d_ws, size_t ws_size,
                              hipStream_t stream) {
    const float* in   = (const float*)d_in[0];   // (16,64,64,128)
    const float* wk   = (const float*)d_in[1];   // (3,3,128,256)
    const float* bias = (const float*)d_in[2];   // (256,)
    float* out = (float*)d_out;
    char* ws = (char*)d_ws;

    // workspace layout (bytes)
    const size_t OFF_PAD = 0;                    // 16*66*66*128*2 = 17,842,176
    const size_t OFF_BF  = 17842176;             // 294912*2       =    589,824
    const size_t OFF_X   = 18432000;             // 16*4096*256*2  = 33,554,432
    const size_t OFF_ST  = 51986432;             // s0,s2,s3,bar   = 12544*4
    const size_t NEEDED  = OFF_ST + 12544 * 4;
    if (ws_size < NEEDED) return;                // fail loudly (validation error)

    u16* pad = (u16*)(ws + OFF_PAD);
    u16* BF  = (u16*)(ws + OFF_BF);
    u16* X   = (u16*)(ws + OFF_X);
    float* s0 = (float*)(ws + OFF_ST);
    float* s2 = s0 + 4096;
    float* s3 = s2 + 4096;
    u32*  bar = (u32*)(s3 + 4096);               // zeroed by k_prep section C

    k_prep <<<5557, 256, 0, stream>>>(in, wk, pad, BF, s0);
    k_conv <<<1024, 256, 0, stream>>>(pad, BF, bias, X, s0);
    k_route<<<512,  256, 0, stream>>>(X, s0, s2, s3, bar, out);
}

// Round 9
// 162.731 us; speedup vs baseline: 1.7936x; 1.7936x over previous
//
#include <hip/hip_runtime.h>
#include <hip/hip_bf16.h>

typedef unsigned short u16;
typedef unsigned int   u32;

typedef __bf16 bf16x8 __attribute__((ext_vector_type(8)));
typedef float  f32x4  __attribute__((ext_vector_type(4)));

#define GLDS(gp, lp) __builtin_amdgcn_global_load_lds( \
    (const __attribute__((address_space(1))) void*)(gp), \
    (__attribute__((address_space(3))) void*)(lp), 16, 0, 0)

__device__ __forceinline__ u16 f2b(float f) {
    __hip_bfloat16 h = __float2bfloat16(f);
    u16 u; __builtin_memcpy(&u, &h, 2); return u;
}
__device__ __forceinline__ float blo(u32 u) { return __uint_as_float(u << 16); }
__device__ __forceinline__ float bhi(u32 u) { return __uint_as_float(u & 0xffff0000u); }

// ---------------------------------------------------------------------------
// fused prep:
//  section A (blocks [0,4356)):    zero-padded bf16 input (16,66,66,128)
//  section B (blocks [4356,5508)): weights -> MFMA B-fragment order
//       BF[(((p*4+kk)*4+q)*256 + n)*8 + j] = bf16(w[(p*128+kk*32+q*8+j)*256+n])
//  section C (blocks [5508,5556)): zero s0,s2,s3 (12288 floats)
// ---------------------------------------------------------------------------
__global__ void k_prep(const float* __restrict__ in, const float* __restrict__ wk,
                       u16* __restrict__ pad, u16* __restrict__ BF,
                       float* __restrict__ stats) {
    int bx = blockIdx.x, tid = threadIdx.x;
    if (bx < 4356) {
        int idx = bx * 256 + tid;                 // one 8-channel chunk each
        int e0  = idx * 8;
        int ch  = e0 & 127;
        int rest = e0 >> 7;                       // (b*66+ph)*66+pw
        int pw = rest % 66;
        int r2 = rest / 66;
        int ph = r2 % 66;
        int b  = r2 / 66;
        u16 ov[8];
        if (ph >= 1 && ph <= 64 && pw >= 1 && pw <= 64) {
            const float* src = in + (((b * 64 + (ph - 1)) * 64 + (pw - 1)) * 128 + ch);
            const float4* s4 = (const float4*)src;
            float4 f0 = s4[0], f1 = s4[1];
            ov[0]=f2b(f0.x); ov[1]=f2b(f0.y); ov[2]=f2b(f0.z); ov[3]=f2b(f0.w);
            ov[4]=f2b(f1.x); ov[5]=f2b(f1.y); ov[6]=f2b(f1.z); ov[7]=f2b(f1.w);
        } else {
            #pragma unroll
            for (int j = 0; j < 8; ++j) ov[j] = 0;
        }
        uint4 w; __builtin_memcpy(&w, ov, 16);
        *(uint4*)(pad + e0) = w;
    } else if (bx < 5508) {
        int t = (bx - 4356) * 256 + tid;          // 294912 total, exact
        int j  = t & 7;
        int n  = (t >> 3) & 255;
        int q  = (t >> 11) & 3;
        int kk = (t >> 13) & 3;
        int p  = t >> 15;
        BF[t] = f2b(wk[(p * 128 + kk * 32 + q * 8 + j) * 256 + n]);
    } else {
        stats[(bx - 5508) * 256 + tid] = 0.f;     // 12288 floats
    }
}

// ---------------------------------------------------------------------------
// conv: implicit GEMM (R4 structure — best measured, no spill, 53 us).
// Block = one image row: M=64, N=256, K=1152. 4 waves, wave tile 64x64
// (4x4 16x16x32 bf16 MFMA). A staged by channel half (25344 B LDS, swizzled
// source gather); B fragments straight from L2 in fragment order, register
// ping-pong, barrier-free K-loop.
// Epilogue: +bias, relu, store x bf16, atomically accumulate s0 = sum_n x.
// ---------------------------------------------------------------------------
__launch_bounds__(256, 2)
__global__ void k_conv(const u16* __restrict__ Ap, const u16* __restrict__ BF,
                       const float* __restrict__ bias,
                       u16* __restrict__ X, float* __restrict__ s0) {
    __shared__ u16 ldsA[12672];                   // 3*66*8 chunks = 25344 B
    const int t = threadIdx.x;
    const int lane = t & 63, wid = t >> 6;        // 4 waves
    const int q = lane >> 4, l15 = lane & 15;
    const int bb = blockIdx.x >> 6;               // batch
    const int h  = blockIdx.x & 63;               // output row
    const int wn0 = wid << 6;                     // wave's n-offset (64 each)

    // stage channel-half S: LDS[pr][wp][cs] = G[S*8 + (cs^(wp&7))] (src swizzle)
#define STAGE(S) { \
    const int sb0 = wid * 396; \
    _Pragma("unroll") for (int i = 0; i < 6; ++i) { \
        int sb = sb0 + i * 64; \
        int slot = sb + lane; \
        int pr = slot / 528; int rem = slot - pr * 528; \
        int wp = rem >> 3, cs = rem & 7; \
        int gc = (S) * 8 + (cs ^ (wp & 7)); \
        const u16* g = Ap + ((((bb * 66 + h + pr) * 66 + wp) << 7) + (gc << 3)); \
        GLDS(g, (char*)ldsA + sb * 16); \
    } \
    { int sb = sb0 + 384; \
      if (lane < 12) { \
        int slot = sb + lane; \
        int pr = slot / 528; int rem = slot - pr * 528; \
        int wp = rem >> 3, cs = rem & 7; \
        int gc = (S) * 8 + (cs ^ (wp & 7)); \
        const u16* g = Ap + ((((bb * 66 + h + pr) * 66 + wp) << 7) + (gc << 3)); \
        GLDS(g, (char*)ldsA + sb * 16); \
      } } }

#define LOADB(B, P, S) { \
    _Pragma("unroll") for (int kk = 0; kk < 2; ++kk) \
    _Pragma("unroll") for (int ni = 0; ni < 4; ++ni) \
        B[kk * 4 + ni] = *(const bf16x8*)(BFl + (P) * 32768 + \
                                          ((S) * 2 + kk) * 8192 + ni * 128); }

#define COMPP(B, DH, DW) { \
    _Pragma("unroll") for (int kk = 0; kk < 2; ++kk) { \
        bf16x8 af[4]; \
        _Pragma("unroll") for (int mi = 0; mi < 4; ++mi) { \
            int wp = mi * 16 + l15 + (DW); \
            int swz = (kk * 4 + q) ^ (wp & 7); \
            af[mi] = *(const bf16x8*)((const char*)ldsA + \
                (((DH) * 528 + wp * 8 + swz) << 4)); \
        } \
        _Pragma("unroll") for (int mi = 0; mi < 4; ++mi) \
        _Pragma("unroll") for (int ni = 0; ni < 4; ++ni) \
            acc[mi][ni] = __builtin_amdgcn_mfma_f32_16x16x32_bf16( \
                af[mi], B[kk * 4 + ni], acc[mi][ni], 0, 0, 0); } }

    const u16* BFl = BF + (q * 2048 + (wn0 + l15) * 8);

    f32x4 zero = {0.f, 0.f, 0.f, 0.f};
    f32x4 acc[4][4];
    #pragma unroll
    for (int mi = 0; mi < 4; ++mi)
        #pragma unroll
        for (int ni = 0; ni < 4; ++ni) acc[mi][ni] = zero;

    bf16x8 B0[8], B1[8];

    // ---- channel half 0 ----
    STAGE(0);
    __syncthreads();
    LOADB(B0, 0, 0);
    LOADB(B1, 1, 0); COMPP(B0, 0, 0);
    LOADB(B0, 2, 0); COMPP(B1, 0, 1);
    LOADB(B1, 3, 0); COMPP(B0, 0, 2);
    LOADB(B0, 4, 0); COMPP(B1, 1, 0);
    LOADB(B1, 5, 0); COMPP(B0, 1, 1);
    LOADB(B0, 6, 0); COMPP(B1, 1, 2);
    LOADB(B1, 7, 0); COMPP(B0, 2, 0);
    LOADB(B0, 8, 0); COMPP(B1, 2, 1);
    COMPP(B0, 2, 2);
    __syncthreads();                              // all half-0 LDS reads done

    // ---- channel half 1 ----
    STAGE(1);
    __syncthreads();
    LOADB(B0, 0, 1);
    LOADB(B1, 1, 1); COMPP(B0, 0, 0);
    LOADB(B0, 2, 1); COMPP(B1, 0, 1);
    LOADB(B1, 3, 1); COMPP(B0, 0, 2);
    LOADB(B0, 4, 1); COMPP(B1, 1, 0);
    LOADB(B1, 5, 1); COMPP(B0, 1, 1);
    LOADB(B0, 6, 1); COMPP(B1, 1, 2);
    LOADB(B1, 7, 1); COMPP(B0, 2, 0);
    LOADB(B0, 8, 1); COMPP(B1, 2, 1);
    COMPP(B0, 2, 2);

    // epilogue: bias + relu, store bf16 x, column sums -> s0
    float bv[4];
    #pragma unroll
    for (int ni = 0; ni < 4; ++ni) bv[ni] = bias[wn0 + ni * 16 + l15];
    float colsum[4] = {0.f, 0.f, 0.f, 0.f};
    u16* xrow = X + (((bb << 12) + (h << 6) + q * 4) * 256) + wn0 + l15;
    #pragma unroll
    for (int mi = 0; mi < 4; ++mi) {
        #pragma unroll
        for (int rr = 0; rr < 4; ++rr) {
            u16* xp = xrow + (mi * 16 + rr) * 256;
            #pragma unroll
            for (int ni = 0; ni < 4; ++ni) {
                float v = acc[mi][ni][rr] + bv[ni];
                v = v > 0.f ? v : 0.f;
                xp[ni * 16] = f2b(v);
                colsum[ni] += v;
            }
        }
    }
    #pragma unroll
    for (int ni = 0; ni < 4; ++ni) {
        float c = colsum[ni];
        c += __shfl_xor(c, 16);
        c += __shfl_xor(c, 32);
        if (lane < 16) atomicAdd(&s0[bb * 256 + wn0 + ni * 16 + l15], c);
    }
#undef STAGE
#undef LOADB
#undef COMPP
}

// ---------------------------------------------------------------------------
// routing pass v2 (latency-tuned): v1 = l2n(Sa), v2 = l2n(Sb) [if use2];
// b = x.v1 (+ x.v2), c = softmax_c(b) (b bounded -> no max pass),
// Sout += sum_n c*x.
// Fixes vs v1 (evidence: R8 k_route profile): stride-17 LDS padding
// (conflict-free), v cached in registers (no LDS in hot loop), all 8 X-loads
// prefetched (8 outstanding vs 2), shfl n-reduction instead of 32-way-
// conflicted LDS transpose.  Block = 64 positions; thread (c=t&15, nl=t>>4).
// ---------------------------------------------------------------------------
__launch_bounds__(256, 4)
__global__ void k_pass(const u16* __restrict__ X, const float* __restrict__ Sa,
                       const float* __restrict__ Sb, float* __restrict__ Sout,
                       int use2) {
    __shared__ float v1s[272], v2s[272];          // [cap*17 + d]
    __shared__ float red[4 * 272];                // [wave][c*17 + d]
    const int t = threadIdx.x, b = blockIdx.y, chunk = blockIdx.x;
    const int c = t & 15, nl = t >> 4;
    const int lane = t & 63, wid = t >> 6;
    {
        float sa = Sa[b * 256 + t];
        float ss = sa * sa;
        #pragma unroll
        for (int off = 1; off < 16; off <<= 1) ss += __shfl_xor(ss, off);
        ss = ss < 1e-12f ? 1e-12f : ss;
        v1s[(t >> 4) * 17 + (t & 15)] = sa / sqrtf(ss);
        if (use2) {
            float sb = Sb[b * 256 + t];
            float s2v = sb * sb;
            #pragma unroll
            for (int off = 1; off < 16; off <<= 1) s2v += __shfl_xor(s2v, off);
            s2v = s2v < 1e-12f ? 1e-12f : s2v;
            v2s[(t >> 4) * 17 + (t & 15)] = sb / sqrtf(s2v);
        } else {
            v2s[(t >> 4) * 17 + (t & 15)] = 0.f;
        }
    }
    // prefetch all 4 positions (8 outstanding 16B loads) while v finishes
    const u16* xbase = X + ((b << 12) + chunk * 64 + nl) * 256 + c * 16;
    uint4 pa[8];
    #pragma unroll
    for (int r = 0; r < 4; ++r) {
        pa[2 * r]     = ((const uint4*)(xbase + r * 16 * 256))[0];
        pa[2 * r + 1] = ((const uint4*)(xbase + r * 16 * 256))[1];
    }
    __syncthreads();
    // register-cache this thread's v rows (conflict-free: stride 17)
    float v1r[16], v2r[16];
    #pragma unroll
    for (int d = 0; d < 16; ++d) { v1r[d] = v1s[c * 17 + d]; v2r[d] = v2s[c * 17 + d]; }

    float acc[16];
    #pragma unroll
    for (int d = 0; d < 16; ++d) acc[d] = 0.f;

    #pragma unroll
    for (int r = 0; r < 4; ++r) {
        u32 us[8];
        __builtin_memcpy(us, &pa[2 * r], 32);
        float xf[16];
        #pragma unroll
        for (int j = 0; j < 8; ++j) { xf[2*j] = blo(us[j]); xf[2*j+1] = bhi(us[j]); }
        float d1 = 0.f, d2 = 0.f;
        #pragma unroll
        for (int d = 0; d < 16; ++d) {
            d1 += xf[d] * v1r[d];
            d2 += xf[d] * v2r[d];
        }
        float bvv = use2 ? (d1 + d2) : d1;
        float e = __expf(bvv);                    // |b| small: stable w/o max
        float sm = e;
        #pragma unroll
        for (int off = 1; off < 16; off <<= 1) sm += __shfl_xor(sm, off);
        float w = e / sm;
        #pragma unroll
        for (int d = 0; d < 16; ++d) acc[d] += w * xf[d];
    }
    // reduce over the wave's 4 nl groups (lanes +-16, +-32) -> lanes 0..15
    #pragma unroll
    for (int d = 0; d < 16; ++d) {
        acc[d] += __shfl_xor(acc[d], 16);
        acc[d] += __shfl_xor(acc[d], 32);
    }
    if (lane < 16) {
        #pragma unroll
        for (int d = 0; d < 16; ++d) red[wid * 272 + lane * 17 + d] = acc[d];
    }
    __syncthreads();
    {
        int c2 = t >> 4, d2 = t & 15;
        float tot = red[c2 * 17 + d2]       + red[272 + c2 * 17 + d2]
                  + red[544 + c2 * 17 + d2] + red[816 + c2 * 17 + d2];
        atomicAdd(&Sout[b * 256 + t], tot);
    }
}

// ---------------------------------------------------------------------------
// final: v = l2_normalize(s3), broadcast to (B,64,64,256) fp32.
// v hoisted to a register (loop-invariant per thread); 1024 blocks.
// ---------------------------------------------------------------------------
__launch_bounds__(256, 4)
__global__ void k_bcast(const float* __restrict__ S, float* __restrict__ Out) {
    __shared__ float vls[256];
    int t = threadIdx.x, bx = blockIdx.x, b = blockIdx.y;
    float s = S[b * 256 + t];
    float ss = s * s;
    #pragma unroll
    for (int off = 1; off < 16; off <<= 1) ss += __shfl_xor(ss, off);
    ss = ss < 1e-12f ? 1e-12f : ss;
    vls[t] = s / sqrtf(ss);
    __syncthreads();
    float4 myv = ((const float4*)vls)[t & 63];    // (j*256+t)&63 == t&63
    float4* o = (float4*)Out + (long)b * 262144 + bx * 4096;
    #pragma unroll
    for (int j = 0; j < 16; ++j) o[j * 256 + t] = myv;
}

// ---------------------------------------------------------------------------
extern "C" void kernel_launch(void* const* d_in, const int* in_sizes, int n_in,
                              void* d_out, int out_size, void* d_ws, size_t ws_size,
                              hipStream_t stream) {
    const float* in   = (const float*)d_in[0];   // (16,64,64,128)
    const float* wk   = (const float*)d_in[1];   // (3,3,128,256)
    const float* bias = (const float*)d_in[2];   // (256,)
    float* out = (float*)d_out;
    char* ws = (char*)d_ws;

    // workspace layout (bytes)
    const size_t OFF_PAD = 0;                    // 16*66*66*128*2 = 17,842,176
    const size_t OFF_BF  = 17842176;             // 294912*2       =    589,824
    const size_t OFF_X   = 18432000;             // 16*4096*256*2  = 33,554,432
    const size_t OFF_ST  = 51986432;             // s0,s2,s3       = 3*16,384
    const size_t NEEDED  = OFF_ST + 3 * 16384;
    if (ws_size < NEEDED) return;                // fail loudly (validation error)

    u16* pad = (u16*)(ws + OFF_PAD);
    u16* BF  = (u16*)(ws + OFF_BF);
    u16* X   = (u16*)(ws + OFF_X);
    float* s0 = (float*)(ws + OFF_ST);
    float* s2 = s0 + 4096;
    float* s3 = s2 + 4096;

    k_prep <<<5556, 256, 0, stream>>>(in, wk, pad, BF, s0);
    k_conv <<<1024, 256, 0, stream>>>(pad, BF, bias, X, s0);
    k_pass <<<dim3(64, 16), 256, 0, stream>>>(X, s0, s0, s2, 0);
    k_pass <<<dim3(64, 16), 256, 0, stream>>>(X, s0, s2, s3, 1);
    k_bcast<<<dim3(64, 16), 256, 0, stream>>>(s3, out);
}